// Round 1
// baseline (1485.389 us; speedup 1.0000x reference)
//
#include <hip/hip_runtime.h>
#include <hip/hip_bf16.h>
#include <math.h>

#define N_NODES 50000
#define N_EDGES 800000
#define TOT_EDGES (N_EDGES + N_NODES)
#define NEG_SLOPE 0.2f

// ---------------- CSR build ----------------

__global__ void hist_kernel(const int* __restrict__ ei, int* __restrict__ counts){
  int e = blockIdx.x*256 + threadIdx.x;
  if (e >= TOT_EDGES) return;
  int d = (e < N_EDGES) ? ei[N_EDGES + e] : (e - N_EDGES);
  atomicAdd(&counts[d], 1);
}

__global__ void scan_kernel(const int* __restrict__ counts, int* __restrict__ offsets,
                            int* __restrict__ cursor){
  __shared__ int sm[1024];
  __shared__ int carry_s;
  int t = threadIdx.x;
  if (t == 0){ carry_s = 0; offsets[0] = 0; }
  __syncthreads();
  for (int base = 0; base < N_NODES; base += 1024){
    int idx = base + t;
    int v = (idx < N_NODES) ? counts[idx] : 0;
    sm[t] = v;
    __syncthreads();
    for (int off = 1; off < 1024; off <<= 1){
      int u = (t >= off) ? sm[t-off] : 0;
      __syncthreads();
      sm[t] += u;
      __syncthreads();
    }
    int inc = sm[t] + carry_s;
    if (idx < N_NODES){ offsets[idx+1] = inc; cursor[idx] = inc - v; }
    __syncthreads();
    if (t == 1023) carry_s = inc;
    __syncthreads();
  }
}

__global__ void scatter_kernel(const int* __restrict__ ei, int* __restrict__ cursor,
                               int* __restrict__ ssrc){
  int e = blockIdx.x*256 + threadIdx.x;
  if (e >= TOT_EDGES) return;
  int s, d;
  if (e < N_EDGES){ s = ei[e]; d = ei[N_EDGES+e]; } else { s = e - N_EDGES; d = s; }
  int pos = atomicAdd(&cursor[d], 1);
  ssrc[pos] = s;
}

// ---------------- f32 GEMM: C[M,N] = A[M,K] @ B[K,N] ----------------

__global__ __launch_bounds__(256) void gemm_kernel(const float* __restrict__ A,
                                                   const float* __restrict__ B,
                                                   float* __restrict__ C,
                                                   int M, int K, int N){
  __shared__ float As[16][65];
  __shared__ float Bs[16][64];
  int tid = threadIdx.x;
  int tx = tid & 15, ty = tid >> 4;
  int bm = blockIdx.y * 64, bn = blockIdx.x * 64;
  float acc[4][4] = {};
  for (int k0 = 0; k0 < K; k0 += 16){
    #pragma unroll
    for (int i = 0; i < 4; ++i){
      int idx = tid + i*256;
      int r = idx >> 4, c = idx & 15;
      int gm = bm + r;
      As[c][r] = (gm < M) ? A[(size_t)gm*K + k0 + c] : 0.f;
    }
    #pragma unroll
    for (int i = 0; i < 4; ++i){
      int idx = tid + i*256;
      int r = idx >> 6, c = idx & 63;
      int gn = bn + c;
      Bs[r][c] = (gn < N) ? B[(size_t)(k0 + r)*N + gn] : 0.f;
    }
    __syncthreads();
    #pragma unroll
    for (int k = 0; k < 16; ++k){
      float a[4], b[4];
      #pragma unroll
      for (int i = 0; i < 4; ++i) a[i] = As[k][ty*4+i];
      #pragma unroll
      for (int j = 0; j < 4; ++j) b[j] = Bs[k][tx*4+j];
      #pragma unroll
      for (int i = 0; i < 4; ++i)
        #pragma unroll
        for (int j = 0; j < 4; ++j)
          acc[i][j] += a[i]*b[j];
    }
    __syncthreads();
  }
  #pragma unroll
  for (int i = 0; i < 4; ++i){
    int gm = bm + ty*4 + i;
    if (gm >= M) continue;
    #pragma unroll
    for (int j = 0; j < 4; ++j){
      int gn = bn + tx*4 + j;
      if (gn < N) C[(size_t)gm*N + gn] = acc[i][j];
    }
  }
}

// ---------------- attention coefficients, H=8 C=64 ----------------

__global__ void attn_coef_kernel(const float* __restrict__ F, const float* __restrict__ att_s,
                                 const float* __restrict__ att_d,
                                 float* __restrict__ asrc, float* __restrict__ adst){
  int gid = blockIdx.x*256 + threadIdx.x;
  int node = gid >> 6;
  int lane = threadIdx.x & 63;
  if (node >= N_NODES) return;
  const float* row = F + (size_t)node*512;
  #pragma unroll
  for (int h = 0; h < 8; ++h){
    float c = row[h*64 + lane];
    float vs = c * att_s[h*64 + lane];
    float vd = c * att_d[h*64 + lane];
    #pragma unroll
    for (int off = 32; off > 0; off >>= 1){
      vs += __shfl_down(vs, off);
      vd += __shfl_down(vd, off);
    }
    if (lane == 0){ asrc[node*8+h] = vs; adst[node*8+h] = vd; }
  }
}

// ---------------- per-dst aggregation, H=8 C=64 (D=512) ----------------

__global__ __launch_bounds__(256) void aggregate_kernel(const float* __restrict__ F,
    const int* __restrict__ offsets, const int* __restrict__ ssrc,
    const float* __restrict__ asrc, const float* __restrict__ adst,
    const float* __restrict__ bias, float* __restrict__ OUT, int do_relu){
  int d = blockIdx.x;
  int t = threadIdx.x;
  int beg = offsets[d], end = offsets[d+1];
  int deg = end - beg;
  __shared__ float red[256];
  __shared__ float mh[8], invd[8];
  __shared__ float al[32][8];
  __shared__ int sArr[32];
  int hh = t & 7, grp = t >> 3;
  float ad = adst[d*8 + hh];
  // pass 1: per-head max
  float pm = -1e30f;
  for (int i = grp; i < deg; i += 32){
    int s = ssrc[beg+i];
    float e = asrc[s*8+hh] + ad;
    e = (e > 0.f) ? e : NEG_SLOPE*e;
    pm = fmaxf(pm, e);
  }
  red[t] = pm; __syncthreads();
  #pragma unroll
  for (int off = 128; off >= 8; off >>= 1){
    if (t < off) red[t] = fmaxf(red[t], red[t+off]);
    __syncthreads();
  }
  if (t < 8) mh[t] = red[t];
  __syncthreads();
  // pass 2: per-head sum of exp
  float m = mh[hh];
  float ps = 0.f;
  for (int i = grp; i < deg; i += 32){
    int s = ssrc[beg+i];
    float e = asrc[s*8+hh] + ad;
    e = (e > 0.f) ? e : NEG_SLOPE*e;
    ps += __expf(e - m);
  }
  red[t] = ps; __syncthreads();
  #pragma unroll
  for (int off = 128; off >= 8; off >>= 1){
    if (t < off) red[t] += red[t+off];
    __syncthreads();
  }
  if (t < 8) invd[t] = 1.f / red[t];
  __syncthreads();
  // pass 3: accumulate  (thread t owns channels t and t+256)
  int c0 = t, c1 = t + 256;
  int h0 = t >> 6, h1 = h0 + 4;
  float acc0 = 0.f, acc1 = 0.f;
  for (int i0 = 0; i0 < deg; i0 += 32){
    int nch = min(32, deg - i0);
    float alv = 0.f;
    if (grp < nch){
      int s = ssrc[beg + i0 + grp];
      float e = asrc[s*8+hh] + ad;
      e = (e > 0.f) ? e : NEG_SLOPE*e;
      alv = __expf(e - mh[hh]) * invd[hh];
      if (hh == 0) sArr[grp] = s;
    }
    al[grp][hh] = alv;
    __syncthreads();
    for (int i = 0; i < nch; ++i){
      const float* fr = F + (size_t)sArr[i]*512;
      acc0 += al[i][h0] * fr[c0];
      acc1 += al[i][h1] * fr[c1];
    }
    __syncthreads();
  }
  float o0 = acc0 + bias[c0], o1 = acc1 + bias[c1];
  if (do_relu){ o0 = fmaxf(o0, 0.f); o1 = fmaxf(o1, 0.f); }
  OUT[(size_t)d*512 + c0] = o0;
  OUT[(size_t)d*512 + c1] = o1;
}

// ---------------- layer 2: H=1 C=40 ----------------

__global__ void attn_coef2_kernel(const float* __restrict__ H2v, const float* __restrict__ as2,
                                  const float* __restrict__ ad2,
                                  float* __restrict__ asrc, float* __restrict__ adst){
  int gid = blockIdx.x*256 + threadIdx.x;
  int node = gid >> 6;
  int lane = threadIdx.x & 63;
  if (node >= N_NODES) return;
  float v = 0.f, ws = 0.f, wd = 0.f;
  if (lane < 40){ v = H2v[(size_t)node*40 + lane]; ws = as2[lane]; wd = ad2[lane]; }
  float vs = v*ws, vd = v*wd;
  #pragma unroll
  for (int off = 32; off > 0; off >>= 1){
    vs += __shfl_down(vs, off);
    vd += __shfl_down(vd, off);
  }
  if (lane == 0){ asrc[node] = vs; adst[node] = vd; }
}

__global__ __launch_bounds__(64) void aggregate2_kernel(const float* __restrict__ H2v,
    const int* __restrict__ offsets, const int* __restrict__ ssrc,
    const float* __restrict__ asrc, const float* __restrict__ adst,
    const float* __restrict__ bias, float* __restrict__ OUT){
  int d = blockIdx.x;
  int lane = threadIdx.x;
  int beg = offsets[d], end = offsets[d+1];
  int deg = end - beg;
  float ad = adst[d];
  float pm = -1e30f;
  for (int i = lane; i < deg; i += 64){
    int s = ssrc[beg+i];
    float e = asrc[s] + ad; e = (e>0.f)?e:NEG_SLOPE*e;
    pm = fmaxf(pm, e);
  }
  #pragma unroll
  for (int off = 32; off > 0; off >>= 1) pm = fmaxf(pm, __shfl_xor(pm, off));
  float ps = 0.f;
  for (int i = lane; i < deg; i += 64){
    int s = ssrc[beg+i];
    float e = asrc[s] + ad; e=(e>0.f)?e:NEG_SLOPE*e;
    ps += __expf(e - pm);
  }
  #pragma unroll
  for (int off = 32; off > 0; off >>= 1) ps += __shfl_xor(ps, off);
  float inv = 1.f/ps;
  __shared__ float alS[64];
  __shared__ int sS[64];
  float acc = 0.f;
  for (int i0 = 0; i0 < deg; i0 += 64){
    int nch = min(64, deg - i0);
    if (lane < nch){
      int s = ssrc[beg+i0+lane];
      float e = asrc[s]+ad; e=(e>0.f)?e:NEG_SLOPE*e;
      alS[lane] = __expf(e-pm)*inv;
      sS[lane] = s;
    }
    __syncthreads();
    for (int i = 0; i < nch; ++i){
      if (lane < 40) acc += alS[i] * H2v[(size_t)sS[i]*40 + lane];
    }
    __syncthreads();
  }
  float logit = (lane<40) ? (acc + bias[lane]) : -1e30f;
  float mm = logit;
  #pragma unroll
  for (int off = 32; off > 0; off >>= 1) mm = fmaxf(mm, __shfl_xor(mm, off));
  float ex = (lane<40) ? __expf(logit-mm) : 0.f;
  float ss = ex;
  #pragma unroll
  for (int off = 32; off > 0; off >>= 1) ss += __shfl_xor(ss, off);
  if (lane < 40) OUT[(size_t)d*40 + lane] = logit - mm - logf(ss);
}

// ---------------- launch ----------------

extern "C" void kernel_launch(void* const* d_in, const int* in_sizes, int n_in,
                              void* d_out, int out_size, void* d_ws, size_t ws_size,
                              hipStream_t stream){
  const float* x   = (const float*)d_in[0];
  const int*   ei  = (const int*)d_in[1];
  const float* W0  = (const float*)d_in[2];
  const float* as0 = (const float*)d_in[3];
  const float* ad0 = (const float*)d_in[4];
  const float* b0  = (const float*)d_in[5];
  const float* W1  = (const float*)d_in[6];
  const float* as1 = (const float*)d_in[7];
  const float* ad1 = (const float*)d_in[8];
  const float* b1  = (const float*)d_in[9];
  const float* W2  = (const float*)d_in[10];
  const float* as2 = (const float*)d_in[11];
  const float* ad2 = (const float*)d_in[12];
  const float* b2  = (const float*)d_in[13];
  float* out = (float*)d_out;

  char* p = (char*)d_ws;
  auto alloc = [&](size_t bytes)->void*{
    void* r = (void*)p; p += (bytes + 255) & ~(size_t)255; return r;
  };
  float* F0    = (float*)alloc((size_t)N_NODES*512*4);
  float* F1    = (float*)alloc((size_t)N_NODES*512*4);
  float* ASRC  = (float*)alloc((size_t)N_NODES*8*4);
  float* ADST  = (float*)alloc((size_t)N_NODES*8*4);
  float* H2v   = (float*)alloc((size_t)N_NODES*40*4);
  float* ASRC2 = (float*)alloc((size_t)N_NODES*4);
  float* ADST2 = (float*)alloc((size_t)N_NODES*4);
  int* counts  = (int*)alloc((size_t)N_NODES*4);
  int* offsets = (int*)alloc((size_t)(N_NODES+1)*4);
  int* cursor  = (int*)alloc((size_t)N_NODES*4);
  int* ssrc    = (int*)alloc((size_t)TOT_EDGES*4);

  // CSR build (same graph for all 3 layers)
  hipMemsetAsync(counts, 0, (size_t)N_NODES*4, stream);
  hist_kernel<<<(TOT_EDGES+255)/256, 256, 0, stream>>>(ei, counts);
  scan_kernel<<<1, 1024, 0, stream>>>(counts, offsets, cursor);
  scatter_kernel<<<(TOT_EDGES+255)/256, 256, 0, stream>>>(ei, cursor, ssrc);

  dim3 gemm_block(256);
  int mt = (N_NODES + 63) / 64;

  // layer 0: x[50000,128] @ W0[128,512]
  gemm_kernel<<<dim3(8, mt), gemm_block, 0, stream>>>(x, W0, F0, N_NODES, 128, 512);
  attn_coef_kernel<<<(N_NODES*64+255)/256, 256, 0, stream>>>(F0, as0, ad0, ASRC, ADST);
  aggregate_kernel<<<N_NODES, 256, 0, stream>>>(F0, offsets, ssrc, ASRC, ADST, b0, F1, 1);

  // layer 1: F1[50000,512] @ W1[512,512]
  gemm_kernel<<<dim3(8, mt), gemm_block, 0, stream>>>(F1, W1, F0, N_NODES, 512, 512);
  attn_coef_kernel<<<(N_NODES*64+255)/256, 256, 0, stream>>>(F0, as1, ad1, ASRC, ADST);
  aggregate_kernel<<<N_NODES, 256, 0, stream>>>(F0, offsets, ssrc, ASRC, ADST, b1, F1, 1);

  // layer 2: F1[50000,512] @ W2[512,40]
  gemm_kernel<<<dim3(1, mt), gemm_block, 0, stream>>>(F1, W2, H2v, N_NODES, 512, 40);
  attn_coef2_kernel<<<(N_NODES*64+255)/256, 256, 0, stream>>>(H2v, as2, ad2, ASRC2, ADST2);
  aggregate2_kernel<<<N_NODES, 64, 0, stream>>>(H2v, offsets, ssrc, ASRC2, ADST2, b2, out);
}

// Round 2
// 1091.727 us; speedup vs baseline: 1.3606x; 1.3606x over previous
//
#include <hip/hip_runtime.h>
#include <hip/hip_bf16.h>
#include <math.h>

#define N_NODES 50000
#define N_EDGES 800000
#define TOT_EDGES (N_EDGES + N_NODES)
#define NEG_SLOPE 0.2f
#define M_PAD 50048

typedef __attribute__((ext_vector_type(8))) short bf16x8;
typedef __attribute__((ext_vector_type(4))) float f32x4;

__device__ __forceinline__ unsigned short f2bf(float f){
  union { float f; unsigned u; } x; x.f = f;
  unsigned r = x.u + 0x7FFF + ((x.u >> 16) & 1);
  return (unsigned short)(r >> 16);
}
__device__ __forceinline__ float bf2f(unsigned short h){
  union { unsigned u; float f; } x; x.u = ((unsigned)h) << 16;
  return x.f;
}
__device__ __forceinline__ void gl_lds16(const void* g, void* l){
  __builtin_amdgcn_global_load_lds(
    (const __attribute__((address_space(1))) unsigned int*)g,
    (__attribute__((address_space(3))) unsigned int*)l, 16, 0, 0);
}

// ---------------- CSR build ----------------

__global__ void hist_kernel(const int* __restrict__ ei, int* __restrict__ counts){
  int e = blockIdx.x*256 + threadIdx.x;
  if (e >= TOT_EDGES) return;
  int d = (e < N_EDGES) ? ei[N_EDGES + e] : (e - N_EDGES);
  atomicAdd(&counts[d], 1);
}

__global__ void scan_kernel(const int* __restrict__ counts, int* __restrict__ offsets,
                            int* __restrict__ cursor){
  __shared__ int sm[1024];
  __shared__ int carry_s;
  int t = threadIdx.x;
  if (t == 0){ carry_s = 0; offsets[0] = 0; }
  __syncthreads();
  for (int base = 0; base < N_NODES; base += 1024){
    int idx = base + t;
    int v = (idx < N_NODES) ? counts[idx] : 0;
    sm[t] = v;
    __syncthreads();
    for (int off = 1; off < 1024; off <<= 1){
      int u = (t >= off) ? sm[t-off] : 0;
      __syncthreads();
      sm[t] += u;
      __syncthreads();
    }
    int inc = sm[t] + carry_s;
    if (idx < N_NODES){ offsets[idx+1] = inc; cursor[idx] = inc - v; }
    __syncthreads();
    if (t == 1023) carry_s = inc;
    __syncthreads();
  }
}

__global__ void scatter_kernel(const int* __restrict__ ei, int* __restrict__ cursor,
                               int* __restrict__ ssrc){
  int e = blockIdx.x*256 + threadIdx.x;
  if (e >= TOT_EDGES) return;
  int s, d;
  if (e < N_EDGES){ s = ei[e]; d = ei[N_EDGES+e]; } else { s = e - N_EDGES; d = s; }
  int pos = atomicAdd(&cursor[d], 1);
  ssrc[pos] = s;
}

// ---------------- weight split+transpose: BT[n][k] = B[k][n] as bf16 hi/lo ----------------

__global__ void convert_BT(const float* __restrict__ B, unsigned short* __restrict__ BTh,
                           unsigned short* __restrict__ BTl, int K, int N){
  int id = blockIdx.x*256 + threadIdx.x;
  if (id >= K*N) return;
  int n = id / K, k = id - n*K;
  float v = B[(size_t)k*N + n];
  unsigned short h = f2bf(v);
  unsigned short l = f2bf(v - bf2f(h));
  BTh[id] = h; BTl[id] = l;
}

// ---------------- split-bf16 MFMA GEMM: C[M,N] = A[M,K] @ BT[N,K]^T ----------------
// 128x128 tile, BK=32, 4 waves, 3-term split (Ah*Bh + Al*Bh + Ah*Bl)

__global__ __launch_bounds__(256, 2) void mfma_gemm(
    const float* __restrict__ A, const unsigned short* __restrict__ BTh,
    const unsigned short* __restrict__ BTl, float* __restrict__ C,
    int M, int K, int N)
{
  __shared__ unsigned short sAh[128*32];
  __shared__ unsigned short sAl[128*32];
  __shared__ unsigned short sBh[128*32];
  __shared__ unsigned short sBl[128*32];

  const int tid = threadIdx.x;
  const int lane = tid & 63;
  const int wid = tid >> 6;
  const int wr = wid >> 1, wc = wid & 1;
  const int bm = blockIdx.y * 128, bn = blockIdx.x * 128;
  const int lr = lane & 15, kg = lane >> 4;

  // A staging: 4 chunks of 4 f32 per thread; swizzled ds_write target
  const float* aread[4];
  int awoff[4];
  #pragma unroll
  for (int i = 0; i < 4; ++i){
    int o = tid + i*256;
    int row = o >> 3, ch = o & 7;
    int gr = bm + row; if (gr > M-1) gr = M-1;   // clamp: no OOB read on input
    aread[i] = A + (size_t)gr*K + ch*4;
    int sc = (ch >> 1) ^ ((row >> 1) & 3);
    awoff[i] = row*32 + sc*8 + (ch & 1)*4;
  }
  // B staging: global_load_lds with pre-swizzled global source (rule #21)
  size_t bgoff[2];
  #pragma unroll
  for (int i = 0; i < 2; ++i){
    int o = tid + i*256;
    int row = o >> 2, ch = o & 3;
    int sc = ch ^ ((row >> 1) & 3);
    bgoff[i] = (size_t)(bn + row)*K + sc*8;
  }
  // fragment ds_read offsets (swizzled), constant across k-steps
  int aoff[4], boff[4];
  #pragma unroll
  for (int i = 0; i < 4; ++i){
    int row = wr*64 + i*16 + lr;
    aoff[i] = row*32 + (kg ^ ((row >> 1) & 3))*8;
    int col = wc*64 + i*16 + lr;
    boff[i] = col*32 + (kg ^ ((col >> 1) & 3))*8;
  }

  float4 areg[4];
  auto loadA = [&](int k0){
    #pragma unroll
    for (int i = 0; i < 4; ++i)
      areg[i] = *(const float4*)(aread[i] + k0);
  };
  auto writeA = [&](){
    #pragma unroll
    for (int i = 0; i < 4; ++i){
      float4 v = areg[i];
      ushort4 h, l;
      h.x = f2bf(v.x); l.x = f2bf(v.x - bf2f(h.x));
      h.y = f2bf(v.y); l.y = f2bf(v.y - bf2f(h.y));
      h.z = f2bf(v.z); l.z = f2bf(v.z - bf2f(h.z));
      h.w = f2bf(v.w); l.w = f2bf(v.w - bf2f(h.w));
      *(ushort4*)&sAh[awoff[i]] = h;
      *(ushort4*)&sAl[awoff[i]] = l;
    }
  };
  auto stageB = [&](int k0){
    #pragma unroll
    for (int i = 0; i < 2; ++i){
      gl_lds16(BTh + bgoff[i] + k0, &sBh[(tid + i*256)*8]);
      gl_lds16(BTl + bgoff[i] + k0, &sBl[(tid + i*256)*8]);
    }
  };

  f32x4 acc[4][4];
  #pragma unroll
  for (int i = 0; i < 4; ++i)
    #pragma unroll
    for (int j = 0; j < 4; ++j)
      acc[i][j] = (f32x4){0.f, 0.f, 0.f, 0.f};

  loadA(0); writeA(); stageB(0);
  __syncthreads();
  int k0 = 0;
  while (true){
    int kn = k0 + 32;
    if (kn < K) loadA(kn);          // prefetch next A f32 tile to regs (overlaps MFMA)
    bf16x8 ah[4], al[4], bh[4], bl[4];
    #pragma unroll
    for (int i = 0; i < 4; ++i){
      ah[i] = *(const bf16x8*)&sAh[aoff[i]];
      al[i] = *(const bf16x8*)&sAl[aoff[i]];
      bh[i] = *(const bf16x8*)&sBh[boff[i]];
      bl[i] = *(const bf16x8*)&sBl[boff[i]];
    }
    #pragma unroll
    for (int i = 0; i < 4; ++i)
      #pragma unroll
      for (int j = 0; j < 4; ++j){
        acc[i][j] = __builtin_amdgcn_mfma_f32_16x16x32_bf16(ah[i], bh[j], acc[i][j], 0, 0, 0);
        acc[i][j] = __builtin_amdgcn_mfma_f32_16x16x32_bf16(al[i], bh[j], acc[i][j], 0, 0, 0);
        acc[i][j] = __builtin_amdgcn_mfma_f32_16x16x32_bf16(ah[i], bl[j], acc[i][j], 0, 0, 0);
      }
    if (kn >= K) break;
    __syncthreads();
    writeA();
    stageB(kn);
    __syncthreads();
    k0 = kn;
  }
  // epilogue: C/D layout col=lane&15, row=(lane>>4)*4+reg  [m89]
  #pragma unroll
  for (int i = 0; i < 4; ++i){
    int gm0 = bm + wr*64 + i*16 + kg*4;
    #pragma unroll
    for (int j = 0; j < 4; ++j){
      int gn = bn + wc*64 + j*16 + lr;
      #pragma unroll
      for (int r = 0; r < 4; ++r){
        int gm = gm0 + r;
        if (gm < M) C[(size_t)gm*N + gn] = acc[i][j][r];
      }
    }
  }
}

// ---------------- f32 GEMM (layer 2 only: N=40) ----------------

__global__ __launch_bounds__(256) void gemm_kernel(const float* __restrict__ A,
                                                   const float* __restrict__ B,
                                                   float* __restrict__ C,
                                                   int M, int K, int N){
  __shared__ float As[16][65];
  __shared__ float Bs[16][64];
  int tid = threadIdx.x;
  int tx = tid & 15, ty = tid >> 4;
  int bm = blockIdx.y * 64, bn = blockIdx.x * 64;
  float acc[4][4] = {};
  for (int k0 = 0; k0 < K; k0 += 16){
    #pragma unroll
    for (int i = 0; i < 4; ++i){
      int idx = tid + i*256;
      int r = idx >> 4, c = idx & 15;
      int gm = bm + r;
      As[c][r] = (gm < M) ? A[(size_t)gm*K + k0 + c] : 0.f;
    }
    #pragma unroll
    for (int i = 0; i < 4; ++i){
      int idx = tid + i*256;
      int r = idx >> 6, c = idx & 63;
      int gn = bn + c;
      Bs[r][c] = (gn < N) ? B[(size_t)(k0 + r)*N + gn] : 0.f;
    }
    __syncthreads();
    #pragma unroll
    for (int k = 0; k < 16; ++k){
      float a[4], b[4];
      #pragma unroll
      for (int i = 0; i < 4; ++i) a[i] = As[k][ty*4+i];
      #pragma unroll
      for (int j = 0; j < 4; ++j) b[j] = Bs[k][tx*4+j];
      #pragma unroll
      for (int i = 0; i < 4; ++i)
        #pragma unroll
        for (int j = 0; j < 4; ++j)
          acc[i][j] += a[i]*b[j];
    }
    __syncthreads();
  }
  #pragma unroll
  for (int i = 0; i < 4; ++i){
    int gm = bm + ty*4 + i;
    if (gm >= M) continue;
    #pragma unroll
    for (int j = 0; j < 4; ++j){
      int gn = bn + tx*4 + j;
      if (gn < N) C[(size_t)gm*N + gn] = acc[i][j];
    }
  }
}

// ---------------- attention coefficients, H=8 C=64 ----------------

__global__ void attn_coef_kernel(const float* __restrict__ F, const float* __restrict__ att_s,
                                 const float* __restrict__ att_d,
                                 float* __restrict__ asrc, float* __restrict__ adst){
  int gid = blockIdx.x*256 + threadIdx.x;
  int node = gid >> 6;
  int lane = threadIdx.x & 63;
  if (node >= N_NODES) return;
  const float* row = F + (size_t)node*512;
  #pragma unroll
  for (int h = 0; h < 8; ++h){
    float c = row[h*64 + lane];
    float vs = c * att_s[h*64 + lane];
    float vd = c * att_d[h*64 + lane];
    #pragma unroll
    for (int off = 32; off > 0; off >>= 1){
      vs += __shfl_down(vs, off);
      vd += __shfl_down(vd, off);
    }
    if (lane == 0){ asrc[node*8+h] = vs; adst[node*8+h] = vd; }
  }
}

// ---------------- per-dst aggregation, H=8 C=64 (D=512) ----------------

__global__ __launch_bounds__(256) void aggregate_kernel(const float* __restrict__ F,
    const int* __restrict__ offsets, const int* __restrict__ ssrc,
    const float* __restrict__ asrc, const float* __restrict__ adst,
    const float* __restrict__ bias, float* __restrict__ OUT, int do_relu){
  int d = blockIdx.x;
  int t = threadIdx.x;
  int beg = offsets[d], end = offsets[d+1];
  int deg = end - beg;
  __shared__ float red[256];
  __shared__ float mh[8], invd[8];
  __shared__ float al[32][8];
  __shared__ int sArr[32];
  int hh = t & 7, grp = t >> 3;
  float ad = adst[d*8 + hh];
  float pm = -1e30f;
  for (int i = grp; i < deg; i += 32){
    int s = ssrc[beg+i];
    float e = asrc[s*8+hh] + ad;
    e = (e > 0.f) ? e : NEG_SLOPE*e;
    pm = fmaxf(pm, e);
  }
  red[t] = pm; __syncthreads();
  #pragma unroll
  for (int off = 128; off >= 8; off >>= 1){
    if (t < off) red[t] = fmaxf(red[t], red[t+off]);
    __syncthreads();
  }
  if (t < 8) mh[t] = red[t];
  __syncthreads();
  float m = mh[hh];
  float ps = 0.f;
  for (int i = grp; i < deg; i += 32){
    int s = ssrc[beg+i];
    float e = asrc[s*8+hh] + ad;
    e = (e > 0.f) ? e : NEG_SLOPE*e;
    ps += __expf(e - m);
  }
  red[t] = ps; __syncthreads();
  #pragma unroll
  for (int off = 128; off >= 8; off >>= 1){
    if (t < off) red[t] += red[t+off];
    __syncthreads();
  }
  if (t < 8) invd[t] = 1.f / red[t];
  __syncthreads();
  int c0 = t, c1 = t + 256;
  int h0 = t >> 6, h1 = h0 + 4;
  float acc0 = 0.f, acc1 = 0.f;
  for (int i0 = 0; i0 < deg; i0 += 32){
    int nch = min(32, deg - i0);
    float alv = 0.f;
    if (grp < nch){
      int s = ssrc[beg + i0 + grp];
      float e = asrc[s*8+hh] + ad;
      e = (e > 0.f) ? e : NEG_SLOPE*e;
      alv = __expf(e - mh[hh]) * invd[hh];
      if (hh == 0) sArr[grp] = s;
    }
    al[grp][hh] = alv;
    __syncthreads();
    for (int i = 0; i < nch; ++i){
      const float* fr = F + (size_t)sArr[i]*512;
      acc0 += al[i][h0] * fr[c0];
      acc1 += al[i][h1] * fr[c1];
    }
    __syncthreads();
  }
  float o0 = acc0 + bias[c0], o1 = acc1 + bias[c1];
  if (do_relu){ o0 = fmaxf(o0, 0.f); o1 = fmaxf(o1, 0.f); }
  OUT[(size_t)d*512 + c0] = o0;
  OUT[(size_t)d*512 + c1] = o1;
}

// ---------------- layer 2: H=1 C=40 ----------------

__global__ void attn_coef2_kernel(const float* __restrict__ H2v, const float* __restrict__ as2,
                                  const float* __restrict__ ad2,
                                  float* __restrict__ asrc, float* __restrict__ adst){
  int gid = blockIdx.x*256 + threadIdx.x;
  int node = gid >> 6;
  int lane = threadIdx.x & 63;
  if (node >= N_NODES) return;
  float v = 0.f, ws = 0.f, wd = 0.f;
  if (lane < 40){ v = H2v[(size_t)node*40 + lane]; ws = as2[lane]; wd = ad2[lane]; }
  float vs = v*ws, vd = v*wd;
  #pragma unroll
  for (int off = 32; off > 0; off >>= 1){
    vs += __shfl_down(vs, off);
    vd += __shfl_down(vd, off);
  }
  if (lane == 0){ asrc[node] = vs; adst[node] = vd; }
}

__global__ __launch_bounds__(64) void aggregate2_kernel(const float* __restrict__ H2v,
    const int* __restrict__ offsets, const int* __restrict__ ssrc,
    const float* __restrict__ asrc, const float* __restrict__ adst,
    const float* __restrict__ bias, float* __restrict__ OUT){
  int d = blockIdx.x;
  int lane = threadIdx.x;
  int beg = offsets[d], end = offsets[d+1];
  int deg = end - beg;
  float ad = adst[d];
  float pm = -1e30f;
  for (int i = lane; i < deg; i += 64){
    int s = ssrc[beg+i];
    float e = asrc[s] + ad; e = (e>0.f)?e:NEG_SLOPE*e;
    pm = fmaxf(pm, e);
  }
  #pragma unroll
  for (int off = 32; off > 0; off >>= 1) pm = fmaxf(pm, __shfl_xor(pm, off));
  float ps = 0.f;
  for (int i = lane; i < deg; i += 64){
    int s = ssrc[beg+i];
    float e = asrc[s] + ad; e=(e>0.f)?e:NEG_SLOPE*e;
    ps += __expf(e - pm);
  }
  #pragma unroll
  for (int off = 32; off > 0; off >>= 1) ps += __shfl_xor(ps, off);
  float inv = 1.f/ps;
  __shared__ float alS[64];
  __shared__ int sS[64];
  float acc = 0.f;
  for (int i0 = 0; i0 < deg; i0 += 64){
    int nch = min(64, deg - i0);
    if (lane < nch){
      int s = ssrc[beg+i0+lane];
      float e = asrc[s]+ad; e=(e>0.f)?e:NEG_SLOPE*e;
      alS[lane] = __expf(e-pm)*inv;
      sS[lane] = s;
    }
    __syncthreads();
    for (int i = 0; i < nch; ++i){
      if (lane < 40) acc += alS[i] * H2v[(size_t)sS[i]*40 + lane];
    }
    __syncthreads();
  }
  float logit = (lane<40) ? (acc + bias[lane]) : -1e30f;
  float mm = logit;
  #pragma unroll
  for (int off = 32; off > 0; off >>= 1) mm = fmaxf(mm, __shfl_xor(mm, off));
  float ex = (lane<40) ? __expf(logit-mm) : 0.f;
  float ss = ex;
  #pragma unroll
  for (int off = 32; off > 0; off >>= 1) ss += __shfl_xor(ss, off);
  if (lane < 40) OUT[(size_t)d*40 + lane] = logit - mm - logf(ss);
}

// ---------------- launch ----------------

extern "C" void kernel_launch(void* const* d_in, const int* in_sizes, int n_in,
                              void* d_out, int out_size, void* d_ws, size_t ws_size,
                              hipStream_t stream){
  const float* x   = (const float*)d_in[0];
  const int*   ei  = (const int*)d_in[1];
  const float* W0  = (const float*)d_in[2];
  const float* as0 = (const float*)d_in[3];
  const float* ad0 = (const float*)d_in[4];
  const float* b0  = (const float*)d_in[5];
  const float* W1  = (const float*)d_in[6];
  const float* as1 = (const float*)d_in[7];
  const float* ad1 = (const float*)d_in[8];
  const float* b1  = (const float*)d_in[9];
  const float* W2  = (const float*)d_in[10];
  const float* as2 = (const float*)d_in[11];
  const float* ad2 = (const float*)d_in[12];
  const float* b2  = (const float*)d_in[13];
  float* out = (float*)d_out;

  char* p = (char*)d_ws;
  auto alloc = [&](size_t bytes)->void*{
    void* r = (void*)p; p += (bytes + 255) & ~(size_t)255; return r;
  };
  float* F0    = (float*)alloc((size_t)M_PAD*512*4);
  float* F1    = (float*)alloc((size_t)M_PAD*512*4);
  float* ASRC  = (float*)alloc((size_t)N_NODES*8*4);
  float* ADST  = (float*)alloc((size_t)N_NODES*8*4);
  float* H2v   = (float*)alloc((size_t)N_NODES*40*4);
  float* ASRC2 = (float*)alloc((size_t)N_NODES*4);
  float* ADST2 = (float*)alloc((size_t)N_NODES*4);
  int* counts  = (int*)alloc((size_t)N_NODES*4);
  int* offsets = (int*)alloc((size_t)(N_NODES+1)*4);
  int* cursor  = (int*)alloc((size_t)N_NODES*4);
  int* ssrc    = (int*)alloc((size_t)TOT_EDGES*4);
  // BT hi/lo aliased into H2v (disjoint lifetimes: BT dead before H2v written)
  unsigned short* BTh = (unsigned short*)H2v;
  unsigned short* BTl = BTh + 512*512;

  // CSR build (same graph for all 3 layers)
  hipMemsetAsync(counts, 0, (size_t)N_NODES*4, stream);
  hist_kernel<<<(TOT_EDGES+255)/256, 256, 0, stream>>>(ei, counts);
  scan_kernel<<<1, 1024, 0, stream>>>(counts, offsets, cursor);
  scatter_kernel<<<(TOT_EDGES+255)/256, 256, 0, stream>>>(ei, cursor, ssrc);

  int mt = M_PAD / 128;   // 391

  // layer 0: x[50000,128] @ W0[128,512]
  convert_BT<<<(128*512+255)/256, 256, 0, stream>>>(W0, BTh, BTl, 128, 512);
  mfma_gemm<<<dim3(4, mt), 256, 0, stream>>>(x, BTh, BTl, F0, N_NODES, 128, 512);
  attn_coef_kernel<<<(N_NODES*64+255)/256, 256, 0, stream>>>(F0, as0, ad0, ASRC, ADST);
  aggregate_kernel<<<N_NODES, 256, 0, stream>>>(F0, offsets, ssrc, ASRC, ADST, b0, F1, 1);

  // layer 1: F1[50000,512] @ W1[512,512]
  convert_BT<<<(512*512+255)/256, 256, 0, stream>>>(W1, BTh, BTl, 512, 512);
  mfma_gemm<<<dim3(4, mt), 256, 0, stream>>>(F1, BTh, BTl, F0, N_NODES, 512, 512);
  attn_coef_kernel<<<(N_NODES*64+255)/256, 256, 0, stream>>>(F0, as1, ad1, ASRC, ADST);
  aggregate_kernel<<<N_NODES, 256, 0, stream>>>(F0, offsets, ssrc, ASRC, ADST, b1, F1, 1);

  // layer 2: F1[50000,512] @ W2[512,40]  (f32; H2v overwrites the dead BT buffers)
  gemm_kernel<<<dim3(1, (N_NODES+63)/64), 256, 0, stream>>>(F1, W2, H2v, N_NODES, 512, 40);
  attn_coef2_kernel<<<(N_NODES*64+255)/256, 256, 0, stream>>>(H2v, as2, ad2, ASRC2, ADST2);
  aggregate2_kernel<<<N_NODES, 64, 0, stream>>>(H2v, offsets, ssrc, ASRC2, ADST2, b2, out);
}

// Round 3
// 740.369 us; speedup vs baseline: 2.0063x; 1.4746x over previous
//
#include <hip/hip_runtime.h>
#include <hip/hip_bf16.h>
#include <math.h>

#define N_NODES 50000
#define N_EDGES 800000
#define TOT_EDGES (N_EDGES + N_NODES)
#define NEG_SLOPE 0.2f
#define M_PAD 50048
#define N_CHUNKS ((N_NODES + 1023) / 1024)

typedef __attribute__((ext_vector_type(8))) short bf16x8;
typedef __attribute__((ext_vector_type(4))) float f32x4;

__device__ __forceinline__ unsigned short f2bf(float f){
  union { float f; unsigned u; } x; x.f = f;
  unsigned r = x.u + 0x7FFF + ((x.u >> 16) & 1);
  return (unsigned short)(r >> 16);
}
__device__ __forceinline__ float bf2f(unsigned short h){
  union { unsigned u; float f; } x; x.u = ((unsigned)h) << 16;
  return x.f;
}
__device__ __forceinline__ void gl_lds16(const void* g, void* l){
  __builtin_amdgcn_global_load_lds(
    (const __attribute__((address_space(1))) unsigned int*)g,
    (__attribute__((address_space(3))) unsigned int*)l, 16, 0, 0);
}

// ---------------- CSR build ----------------

__global__ void hist_kernel(const int* __restrict__ ei, int* __restrict__ counts){
  int e = blockIdx.x*256 + threadIdx.x;
  if (e >= TOT_EDGES) return;
  int d = (e < N_EDGES) ? ei[N_EDGES + e] : (e - N_EDGES);
  atomicAdd(&counts[d], 1);
}

__global__ void scan1_kernel(const int* __restrict__ counts, int* __restrict__ partial,
                             int* __restrict__ chunksum){
  __shared__ int sm[1024];
  int t = threadIdx.x;
  int idx = blockIdx.x*1024 + t;
  int v = (idx < N_NODES) ? counts[idx] : 0;
  sm[t] = v;
  __syncthreads();
  for (int off = 1; off < 1024; off <<= 1){
    int u = (t >= off) ? sm[t-off] : 0;
    __syncthreads();
    sm[t] += u;
    __syncthreads();
  }
  if (idx < N_NODES) partial[idx] = sm[t];
  if (t == 1023) chunksum[blockIdx.x] = sm[1023];
}

__global__ void scan2_kernel(const int* __restrict__ chunksum, int* __restrict__ carry){
  if (threadIdx.x == 0){
    int c = 0;
    for (int i = 0; i < N_CHUNKS; ++i){ carry[i] = c; c += chunksum[i]; }
  }
}

__global__ void scan3_kernel(const int* __restrict__ partial, const int* __restrict__ counts,
                             const int* __restrict__ carry, int* __restrict__ offsets,
                             int* __restrict__ cursor){
  int idx = blockIdx.x*256 + threadIdx.x;
  if (idx >= N_NODES) return;
  int inc = partial[idx] + carry[idx >> 10];
  offsets[idx+1] = inc;
  cursor[idx] = inc - counts[idx];
  if (idx == 0) offsets[0] = 0;
}

__global__ void scatter_kernel(const int* __restrict__ ei, int* __restrict__ cursor,
                               int* __restrict__ ssrc){
  int e = blockIdx.x*256 + threadIdx.x;
  if (e >= TOT_EDGES) return;
  int s, d;
  if (e < N_EDGES){ s = ei[e]; d = ei[N_EDGES+e]; } else { s = e - N_EDGES; d = s; }
  int pos = atomicAdd(&cursor[d], 1);
  ssrc[pos] = s;
}

// ---------------- weight split+transpose: BT[n][k] = B[k][n] as bf16 hi/lo ----------------

__global__ void convert_BT(const float* __restrict__ B, unsigned short* __restrict__ BTh,
                           unsigned short* __restrict__ BTl, int K, int N){
  int id = blockIdx.x*256 + threadIdx.x;
  if (id >= K*N) return;
  int n = id / K, k = id - n*K;
  float v = B[(size_t)k*N + n];
  unsigned short h = f2bf(v);
  unsigned short l = f2bf(v - bf2f(h));
  BTh[id] = h; BTl[id] = l;
}

// layer-2 weights [512,40] -> padded BT2 [128][512]
__global__ void convert_BT2(const float* __restrict__ B, unsigned short* __restrict__ BTh,
                            unsigned short* __restrict__ BTl){
  int id = blockIdx.x*256 + threadIdx.x;
  if (id >= 128*512) return;
  int n = id >> 9, k = id & 511;
  float v = (n < 40) ? B[(size_t)k*40 + n] : 0.f;
  unsigned short h = f2bf(v);
  unsigned short l = f2bf(v - bf2f(h));
  BTh[id] = h; BTl[id] = l;
}

// ---------------- split-bf16 MFMA GEMM + fused attn-coef + bf16 output ----------------
// 128x128 tile, BK=32, 4 waves, 3-term split (Ah*Bh + Al*Bh + Ah*Bl)

__global__ __launch_bounds__(256, 2) void mfma_gemm(
    const float* __restrict__ A, const unsigned short* __restrict__ BTh,
    const unsigned short* __restrict__ BTl, float* __restrict__ C,
    unsigned short* __restrict__ Fb,
    const float* __restrict__ att_s, const float* __restrict__ att_d,
    float* __restrict__ asrc, float* __restrict__ adst,
    int M, int K, int Nc)
{
  __shared__ unsigned short sAh[128*32];
  __shared__ unsigned short sAl[128*32];
  __shared__ unsigned short sBh[128*32];
  __shared__ unsigned short sBl[128*32];

  const int tid = threadIdx.x;
  const int lane = tid & 63;
  const int wid = tid >> 6;
  const int wr = wid >> 1, wc = wid & 1;
  const int bm = blockIdx.y * 128, bn = blockIdx.x * 128;
  const int lr = lane & 15, kg = lane >> 4;

  // A staging: 4 chunks of 4 f32 per thread; swizzled ds_write target
  const float* aread[4];
  int awoff[4];
  #pragma unroll
  for (int i = 0; i < 4; ++i){
    int o = tid + i*256;
    int row = o >> 3, ch = o & 7;
    int gr = bm + row; if (gr > M-1) gr = M-1;   // clamp: no OOB read on input
    aread[i] = A + (size_t)gr*K + ch*4;
    int sc = (ch >> 1) ^ ((row >> 1) & 3);
    awoff[i] = row*32 + sc*8 + (ch & 1)*4;
  }
  // B staging: global_load_lds with pre-swizzled global source (rule #21)
  size_t bgoff[2];
  #pragma unroll
  for (int i = 0; i < 2; ++i){
    int o = tid + i*256;
    int row = o >> 2, ch = o & 3;
    int sc = ch ^ ((row >> 1) & 3);
    bgoff[i] = (size_t)(bn + row)*K + sc*8;
  }
  // fragment ds_read offsets (swizzled), constant across k-steps
  int aoff[4], boff[4];
  #pragma unroll
  for (int i = 0; i < 4; ++i){
    int row = wr*64 + i*16 + lr;
    aoff[i] = row*32 + (kg ^ ((row >> 1) & 3))*8;
    int col = wc*64 + i*16 + lr;
    boff[i] = col*32 + (kg ^ ((col >> 1) & 3))*8;
  }

  float4 areg[4];
  auto loadA = [&](int k0){
    #pragma unroll
    for (int i = 0; i < 4; ++i)
      areg[i] = *(const float4*)(aread[i] + k0);
  };
  auto writeA = [&](){
    #pragma unroll
    for (int i = 0; i < 4; ++i){
      float4 v = areg[i];
      ushort4 h, l;
      h.x = f2bf(v.x); l.x = f2bf(v.x - bf2f(h.x));
      h.y = f2bf(v.y); l.y = f2bf(v.y - bf2f(h.y));
      h.z = f2bf(v.z); l.z = f2bf(v.z - bf2f(h.z));
      h.w = f2bf(v.w); l.w = f2bf(v.w - bf2f(h.w));
      *(ushort4*)&sAh[awoff[i]] = h;
      *(ushort4*)&sAl[awoff[i]] = l;
    }
  };
  auto stageB = [&](int k0){
    #pragma unroll
    for (int i = 0; i < 2; ++i){
      gl_lds16(BTh + bgoff[i] + k0, &sBh[(tid + i*256)*8]);
      gl_lds16(BTl + bgoff[i] + k0, &sBl[(tid + i*256)*8]);
    }
  };

  f32x4 acc[4][4];
  #pragma unroll
  for (int i = 0; i < 4; ++i)
    #pragma unroll
    for (int j = 0; j < 4; ++j)
      acc[i][j] = (f32x4){0.f, 0.f, 0.f, 0.f};

  loadA(0); writeA(); stageB(0);
  __syncthreads();
  int k0 = 0;
  while (true){
    int kn = k0 + 32;
    if (kn < K) loadA(kn);          // prefetch next A f32 tile to regs (overlaps MFMA)
    bf16x8 ah[4], al[4], bh[4], bl[4];
    #pragma unroll
    for (int i = 0; i < 4; ++i){
      ah[i] = *(const bf16x8*)&sAh[aoff[i]];
      al[i] = *(const bf16x8*)&sAl[aoff[i]];
      bh[i] = *(const bf16x8*)&sBh[boff[i]];
      bl[i] = *(const bf16x8*)&sBl[boff[i]];
    }
    #pragma unroll
    for (int i = 0; i < 4; ++i)
      #pragma unroll
      for (int j = 0; j < 4; ++j){
        acc[i][j] = __builtin_amdgcn_mfma_f32_16x16x32_bf16(ah[i], bh[j], acc[i][j], 0, 0, 0);
        acc[i][j] = __builtin_amdgcn_mfma_f32_16x16x32_bf16(al[i], bh[j], acc[i][j], 0, 0, 0);
        acc[i][j] = __builtin_amdgcn_mfma_f32_16x16x32_bf16(ah[i], bl[j], acc[i][j], 0, 0, 0);
      }
    if (kn >= K) break;
    __syncthreads();
    writeA();
    stageB(kn);
    __syncthreads();
    k0 = kn;
  }

  // fused attention coefficients: each wave owns exactly one head's 64 cols
  if (att_s){
    int head = (bn >> 6) + wc;
    float ws_[4], wd_[4];
    #pragma unroll
    for (int j = 0; j < 4; ++j){
      ws_[j] = att_s[head*64 + j*16 + lr];
      wd_[j] = att_d[head*64 + j*16 + lr];
    }
    #pragma unroll
    for (int i = 0; i < 4; ++i){
      #pragma unroll
      for (int r = 0; r < 4; ++r){
        float vs = 0.f, vd = 0.f;
        #pragma unroll
        for (int j = 0; j < 4; ++j){
          vs += acc[i][j][r] * ws_[j];
          vd += acc[i][j][r] * wd_[j];
        }
        #pragma unroll
        for (int m = 1; m < 16; m <<= 1){
          vs += __shfl_xor(vs, m);
          vd += __shfl_xor(vd, m);
        }
        int gm = bm + wr*64 + i*16 + kg*4 + r;
        if ((lane & 15) == 0 && gm < M){
          asrc[gm*8 + head] = vs;
          adst[gm*8 + head] = vd;
        }
      }
    }
  }

  // epilogue: C/D layout col=lane&15, row=(lane>>4)*4+reg  [m89]
  #pragma unroll
  for (int i = 0; i < 4; ++i){
    int gm0 = bm + wr*64 + i*16 + kg*4;
    #pragma unroll
    for (int j = 0; j < 4; ++j){
      int gn = bn + wc*64 + j*16 + lr;
      #pragma unroll
      for (int r = 0; r < 4; ++r){
        int gm = gm0 + r;
        if (gm < M){
          if (C && gn < Nc) C[(size_t)gm*Nc + gn] = acc[i][j][r];
          if (Fb) Fb[(size_t)gm*512 + gn] = f2bf(acc[i][j][r]);
        }
      }
    }
  }
}

// ---------------- per-dst aggregation, H=8 C=64, bf16 gather ----------------

__global__ __launch_bounds__(256) void aggregate_kernel(const unsigned short* __restrict__ Fb,
    const int* __restrict__ offsets, const int* __restrict__ ssrc,
    const float* __restrict__ asrc, const float* __restrict__ adst,
    const float* __restrict__ bias, float* __restrict__ OUT, int do_relu){
  int d = blockIdx.x;
  int t = threadIdx.x;
  int beg = offsets[d], end = offsets[d+1];
  int deg = end - beg;
  __shared__ float red[256];
  __shared__ float mh[8], invd[8];
  __shared__ float al[32][8];
  __shared__ int sArr[32];
  int hh = t & 7, grp = t >> 3;
  float ad = adst[d*8 + hh];
  // pass 1: per-head max
  float pm = -1e30f;
  for (int i = grp; i < deg; i += 32){
    int s = ssrc[beg+i];
    float e = asrc[s*8+hh] + ad;
    e = (e > 0.f) ? e : NEG_SLOPE*e;
    pm = fmaxf(pm, e);
  }
  red[t] = pm; __syncthreads();
  #pragma unroll
  for (int off = 128; off >= 8; off >>= 1){
    if (t < off) red[t] = fmaxf(red[t], red[t+off]);
    __syncthreads();
  }
  if (t < 8) mh[t] = red[t];
  __syncthreads();
  // pass 2: per-head sum of exp
  float m = mh[hh];
  float ps = 0.f;
  for (int i = grp; i < deg; i += 32){
    int s = ssrc[beg+i];
    float e = asrc[s*8+hh] + ad;
    e = (e > 0.f) ? e : NEG_SLOPE*e;
    ps += __expf(e - m);
  }
  red[t] = ps; __syncthreads();
  #pragma unroll
  for (int off = 128; off >= 8; off >>= 1){
    if (t < off) red[t] += red[t+off];
    __syncthreads();
  }
  if (t < 8) invd[t] = 1.f / red[t];
  __syncthreads();
  // pass 3: accumulate; thread t owns channels 2t, 2t+1 (one uint gather)
  int c = t*2;
  int h = t >> 5;
  float acc0 = 0.f, acc1 = 0.f;
  for (int i0 = 0; i0 < deg; i0 += 32){
    int nch = min(32, deg - i0);
    float alv = 0.f;
    if (grp < nch){
      int s = ssrc[beg + i0 + grp];
      float e = asrc[s*8+hh] + ad;
      e = (e > 0.f) ? e : NEG_SLOPE*e;
      alv = __expf(e - mh[hh]) * invd[hh];
      if (hh == 0) sArr[grp] = s;
    }
    al[grp][hh] = alv;
    __syncthreads();
    #pragma unroll 2
    for (int i = 0; i < nch; ++i){
      unsigned v = *(const unsigned*)&Fb[(size_t)sArr[i]*512 + c];
      union { unsigned u; float f; } lo, hi;
      lo.u = v << 16;
      hi.u = v & 0xffff0000u;
      float a = al[i][h];
      acc0 += a * lo.f;
      acc1 += a * hi.f;
    }
    __syncthreads();
  }
  float2 bb = ((const float2*)bias)[t];
  float o0 = acc0 + bb.x, o1 = acc1 + bb.y;
  if (do_relu){ o0 = fmaxf(o0, 0.f); o1 = fmaxf(o1, 0.f); }
  ((float2*)(OUT + (size_t)d*512))[t] = make_float2(o0, o1);
}

// ---------------- layer 2: H=1 C=40 ----------------

__global__ void attn_coef2_kernel(const float* __restrict__ H2v, const float* __restrict__ as2,
                                  const float* __restrict__ ad2,
                                  float* __restrict__ asrc, float* __restrict__ adst){
  int gid = blockIdx.x*256 + threadIdx.x;
  int node = gid >> 6;
  int lane = threadIdx.x & 63;
  if (node >= N_NODES) return;
  float v = 0.f, ws = 0.f, wd = 0.f;
  if (lane < 40){ v = H2v[(size_t)node*40 + lane]; ws = as2[lane]; wd = ad2[lane]; }
  float vs = v*ws, vd = v*wd;
  #pragma unroll
  for (int off = 32; off > 0; off >>= 1){
    vs += __shfl_down(vs, off);
    vd += __shfl_down(vd, off);
  }
  if (lane == 0){ asrc[node] = vs; adst[node] = vd; }
}

__global__ __launch_bounds__(64) void aggregate2_kernel(const float* __restrict__ H2v,
    const int* __restrict__ offsets, const int* __restrict__ ssrc,
    const float* __restrict__ asrc, const float* __restrict__ adst,
    const float* __restrict__ bias, float* __restrict__ OUT){
  int d = blockIdx.x;
  int lane = threadIdx.x;
  int beg = offsets[d], end = offsets[d+1];
  int deg = end - beg;
  float ad = adst[d];
  float pm = -1e30f;
  for (int i = lane; i < deg; i += 64){
    int s = ssrc[beg+i];
    float e = asrc[s] + ad; e = (e>0.f)?e:NEG_SLOPE*e;
    pm = fmaxf(pm, e);
  }
  #pragma unroll
  for (int off = 32; off > 0; off >>= 1) pm = fmaxf(pm, __shfl_xor(pm, off));
  float ps = 0.f;
  for (int i = lane; i < deg; i += 64){
    int s = ssrc[beg+i];
    float e = asrc[s] + ad; e=(e>0.f)?e:NEG_SLOPE*e;
    ps += __expf(e - pm);
  }
  #pragma unroll
  for (int off = 32; off > 0; off >>= 1) ps += __shfl_xor(ps, off);
  float inv = 1.f/ps;
  __shared__ float alS[64];
  __shared__ int sS[64];
  float acc = 0.f;
  for (int i0 = 0; i0 < deg; i0 += 64){
    int nch = min(64, deg - i0);
    if (lane < nch){
      int s = ssrc[beg+i0+lane];
      float e = asrc[s]+ad; e=(e>0.f)?e:NEG_SLOPE*e;
      alS[lane] = __expf(e-pm)*inv;
      sS[lane] = s;
    }
    __syncthreads();
    for (int i = 0; i < nch; ++i){
      if (lane < 40) acc += alS[i] * H2v[(size_t)sS[i]*40 + lane];
    }
    __syncthreads();
  }
  float logit = (lane<40) ? (acc + bias[lane]) : -1e30f;
  float mm = logit;
  #pragma unroll
  for (int off = 32; off > 0; off >>= 1) mm = fmaxf(mm, __shfl_xor(mm, off));
  float ex = (lane<40) ? __expf(logit-mm) : 0.f;
  float ss = ex;
  #pragma unroll
  for (int off = 32; off > 0; off >>= 1) ss += __shfl_xor(ss, off);
  if (lane < 40) OUT[(size_t)d*40 + lane] = logit - mm - logf(ss);
}

// ---------------- launch ----------------

extern "C" void kernel_launch(void* const* d_in, const int* in_sizes, int n_in,
                              void* d_out, int out_size, void* d_ws, size_t ws_size,
                              hipStream_t stream){
  const float* x   = (const float*)d_in[0];
  const int*   ei  = (const int*)d_in[1];
  const float* W0  = (const float*)d_in[2];
  const float* as0 = (const float*)d_in[3];
  const float* ad0 = (const float*)d_in[4];
  const float* b0  = (const float*)d_in[5];
  const float* W1  = (const float*)d_in[6];
  const float* as1 = (const float*)d_in[7];
  const float* ad1 = (const float*)d_in[8];
  const float* b1  = (const float*)d_in[9];
  const float* W2  = (const float*)d_in[10];
  const float* as2 = (const float*)d_in[11];
  const float* ad2 = (const float*)d_in[12];
  const float* b2  = (const float*)d_in[13];
  float* out = (float*)d_out;

  char* p = (char*)d_ws;
  auto alloc = [&](size_t bytes)->void*{
    void* r = (void*)p; p += (bytes + 255) & ~(size_t)255; return r;
  };
  float* F1    = (float*)alloc((size_t)M_PAD*512*4);      // aggregate output / GEMM A
  unsigned short* Fb = (unsigned short*)alloc((size_t)M_PAD*512*2);  // bf16 h for gather
  float* ASRC  = (float*)alloc((size_t)N_NODES*8*4);
  float* ADST  = (float*)alloc((size_t)N_NODES*8*4);
  float* H2v   = (float*)alloc((size_t)N_NODES*40*4);
  float* ASRC2 = (float*)alloc((size_t)N_NODES*4);
  float* ADST2 = (float*)alloc((size_t)N_NODES*4);
  int* counts  = (int*)alloc((size_t)N_NODES*4);
  int* offsets = (int*)alloc((size_t)(N_NODES+1)*4);
  int* cursor  = (int*)alloc((size_t)N_NODES*4);
  int* ssrc    = (int*)alloc((size_t)TOT_EDGES*4);
  int* partial = (int*)alloc((size_t)N_NODES*4);
  int* chunksum= (int*)alloc(64*4);
  int* carry   = (int*)alloc(64*4);
  unsigned short* BTh  = (unsigned short*)alloc((size_t)512*512*2);
  unsigned short* BTl  = (unsigned short*)alloc((size_t)512*512*2);
  unsigned short* BT2h = (unsigned short*)alloc((size_t)128*512*2);
  unsigned short* BT2l = (unsigned short*)alloc((size_t)128*512*2);

  // CSR build (same graph for all 3 layers)
  hipMemsetAsync(counts, 0, (size_t)N_NODES*4, stream);
  hist_kernel<<<(TOT_EDGES+255)/256, 256, 0, stream>>>(ei, counts);
  scan1_kernel<<<N_CHUNKS, 1024, 0, stream>>>(counts, partial, chunksum);
  scan2_kernel<<<1, 64, 0, stream>>>(chunksum, carry);
  scan3_kernel<<<(N_NODES+255)/256, 256, 0, stream>>>(partial, counts, carry, offsets, cursor);
  scatter_kernel<<<(TOT_EDGES+255)/256, 256, 0, stream>>>(ei, cursor, ssrc);

  int mt = M_PAD / 128;   // 391

  // layer 0: x[50000,128] @ W0[128,512]  (no f32 C; attn fused; bf16 h out)
  convert_BT<<<(128*512+255)/256, 256, 0, stream>>>(W0, BTh, BTl, 128, 512);
  mfma_gemm<<<dim3(4, mt), 256, 0, stream>>>(x, BTh, BTl, nullptr, Fb,
                                             as0, ad0, ASRC, ADST, N_NODES, 128, 512);
  aggregate_kernel<<<N_NODES, 256, 0, stream>>>(Fb, offsets, ssrc, ASRC, ADST, b0, F1, 1);

  // layer 1: F1[50000,512] @ W1[512,512]
  convert_BT<<<(512*512+255)/256, 256, 0, stream>>>(W1, BTh, BTl, 512, 512);
  mfma_gemm<<<dim3(4, mt), 256, 0, stream>>>(F1, BTh, BTl, nullptr, Fb,
                                             as1, ad1, ASRC, ADST, N_NODES, 512, 512);
  aggregate_kernel<<<N_NODES, 256, 0, stream>>>(Fb, offsets, ssrc, ASRC, ADST, b1, F1, 1);

  // layer 2: F1[50000,512] @ W2[512,40]  (mfma with zero-padded B, f32 C out)
  convert_BT2<<<(128*512+255)/256, 256, 0, stream>>>(W2, BT2h, BT2l);
  mfma_gemm<<<dim3(1, mt), 256, 0, stream>>>(F1, BT2h, BT2l, H2v, nullptr,
                                             nullptr, nullptr, nullptr, nullptr, N_NODES, 512, 40);
  attn_coef2_kernel<<<(N_NODES*64+255)/256, 256, 0, stream>>>(H2v, as2, ad2, ASRC2, ADST2);
  aggregate2_kernel<<<N_NODES, 64, 0, stream>>>(H2v, offsets, ssrc, ASRC2, ADST2, b2, out);
}